// Round 13
// baseline (155.117 us; speedup 1.0000x reference)
//
#include <hip/hip_runtime.h>
#include <math.h>

#define DD 64      // feature dim
#define MM 128     // time points per path
#define PSTR 66    // packed-inc plane row stride (u32 words): reads (2r+l)%32, writes <=2-way
#define PWORDS (16 * PSTR)   // 1056 words = 4224 B per wave

typedef float  f32x4v __attribute__((ext_vector_type(4)));
typedef __bf16 bf16x8 __attribute__((ext_vector_type(8)));

#define FOR8(F) F(0) F(1) F(2) F(3) F(4) F(5) F(6) F(7)

union FragU { unsigned int u[4]; bf16x8 v; };

// RNE f32x2 -> packed bf16x2 (lo16 = bf16(%1), hi16 = bf16(%2))
__device__ __forceinline__ unsigned cvtpk(float lo, float hi) {
    unsigned r;
    asm("v_cvt_pk_bf16_f32 %0, %1, %2" : "=v"(r) : "v"(lo), "v"(hi));
    return r;
}

// quad_perm [1,0,3,2]: swap adjacent lanes (lane ^ 1)
__device__ __forceinline__ float qswap(float x) {
    int t = __builtin_amdgcn_update_dpp(0, __float_as_int(x), 0xB1, 0xF, 0xF, true);
    return __int_as_float(t);
}

// bf16 frag of (row1 - row0), 8 consecutive floats (hi bits, RNE)
__device__ __forceinline__ bf16x8 dfrag_hi(const float* __restrict__ r0,
                                           const float* __restrict__ r1) {
    float4 a0 = *(const float4*)r0, a1 = *(const float4*)(r0 + 4);
    float4 b0 = *(const float4*)r1, b1 = *(const float4*)(r1 + 4);
    FragU f;
    f.u[0] = cvtpk(b0.x - a0.x, b0.y - a0.y);
    f.u[1] = cvtpk(b0.z - a0.z, b0.w - a0.w);
    f.u[2] = cvtpk(b1.x - a1.x, b1.y - a1.y);
    f.u[3] = cvtpk(b1.z - a1.z, b1.w - a1.w);
    return f.v;
}

// ---- wave64 inclusive add-scan via DPP (proven rounds 2-12) ----
template<int CTRL, int RM, bool BC>
__device__ __forceinline__ float dpp_add(float x) {
    int t = __builtin_amdgcn_update_dpp(0, __float_as_int(x), CTRL, RM, 0xf, BC);
    return x + __int_as_float(t);
}
__device__ __forceinline__ float wave_incl_scan(float x) {
    x = dpp_add<0x111, 0xf, true >(x);   // row_shr:1
    x = dpp_add<0x112, 0xf, true >(x);   // row_shr:2
    x = dpp_add<0x114, 0xf, true >(x);   // row_shr:4
    x = dpp_add<0x118, 0xf, true >(x);   // row_shr:8
    x = dpp_add<0x142, 0xa, false>(x);   // row_bcast:15 -> rows 1,3
    x = dpp_add<0x143, 0xc, false>(x);   // row_bcast:31 -> rows 2,3
    return x;
}

// ROUND 13: 4 independent waves per 256-thread block, ONE pair per wave, no
// barriers. r8-r12 evidence: resident BLOCKS/CU is soft-capped ~6-9 regardless
// of LDS, so 1-wave blocks cap at ~2.25 waves/SIMD (the 20-30% occupancy wall
// behind every pipe reading <=31% since r6). Fat blocks multiply waves/CU.
// To fit 4 planes in LDS and stay under the (256,4) 128-reg cap: inc stored
// as PACKED bf16 (cvt_pk + DPP quad-swap pairs adjacent cols at write time):
//   plane 16 x 66 u32 = 4.2 KB/wave -> 16.9 KB/block (9 blocks/CU by LDS);
//   scan reads 1 ds_read_b32/row (was 2 b64); banks <=2-way everywhere.
// Precision: +<=0.4% rel on inc atop existing bf16-product error; absmax has
// 10x+ headroom (sentinel). Structure else = r11: B-table in 16 named bf16x8
// regs, A hi-only, DPP-scan Goursat with depth-2 row prefetch.
__global__ __launch_bounds__(256, 4) void sig_goursat_kernel(
        const float* __restrict__ X, const float* __restrict__ Y,
        float* __restrict__ Kout)
{
    const int tid  = threadIdx.x;
    const int wid  = tid >> 6;
    const int lane = tid & 63;
    const int t    = blockIdx.x * 4 + wid;   // global wave id, 0..8255

    int g, a, b;
    if (t < 4160) {                  // symmetric grams, triangular index
        g = t < 2080 ? 0 : 1;
        const int u = t - g * 2080;
        float sq = sqrtf(4160.25f - 2.0f * (float)u);
        a = (int)(64.5f - sq);
        if (a < 0) a = 0; if (a > 63) a = 63;
        while (a > 0  && (a * (129 - a)) / 2 > u) --a;
        while (a < 63 && ((a + 1) * (128 - a)) / 2 <= u) ++a;
        b = a + (u - (a * (129 - a)) / 2);
    } else {
        const int u = t - 4160;
        g = 2; a = u >> 6; b = u & 63;
    }

    const float* __restrict__ U = (g == 1 ? Y : X) + (size_t)a * (MM * DD);
    const float* __restrict__ V = (g == 0 ? X : Y) + (size_t)b * (MM * DD);

    const int l15  = lane & 15;
    const int k8   = (lane >> 4) * 8;         // k-offset of this lane's frag
    const int rowg = (lane >> 4) * 4;         // C/D row group base
    const int par  = l15 & 1;

    __shared__ unsigned incL[4][PWORDS];      // per-wave packed-bf16 inc plane
    unsigned* __restrict__ plane = incL[wid];

    // ---- B-frag register table: 16 named bf16x8 (64 regs), built once ----
#define TBDECL(ct) bf16x8 tb0_##ct, tb1_##ct;
    FOR8(TBDECL)
#define TBUILD(ct) { int brow_ = ct * 16 + l15; if (brow_ > 126) brow_ = 126; \
        const float* vp_ = V + (size_t)brow_ * DD + k8; \
        tb0_##ct = dfrag_hi(vp_,      vp_ + DD); \
        tb1_##ct = dfrag_hi(vp_ + 32, vp_ + DD + 32); }
    FOR8(TBUILD)

    float KL0 = 1.0f, KL1 = 1.0f;             // K[0][2l], K[0][2l+1] = 1

    // writer: even l15 lanes own packs for rows rowg+0/1; odd for rowg+2/3.
    // word = row*PSTR + ct*8 + (l15>>1)
    const int wA = (rowg + 2 * par) * PSTR + (l15 >> 1);
    const int wB = wA + PSTR;

#define CTSTEP(ct) { \
        f32x4v c = {0.f, 0.f, 0.f, 0.f}; \
        c = __builtin_amdgcn_mfma_f32_16x16x32_bf16(ak0, tb0_##ct, c, 0, 0, 0); \
        c = __builtin_amdgcn_mfma_f32_16x16x32_bf16(ak1, tb1_##ct, c, 0, 0, 0); \
        const float n0 = qswap(c[0]); const float n1 = qswap(c[1]); \
        const float n2 = qswap(c[2]); const float n3 = qswap(c[3]); \
        const float loA = par ? n2 : c[0]; const float hiA = par ? c[2] : n0; \
        const float loB = par ? n3 : c[1]; const float hiB = par ? c[3] : n1; \
        plane[wA + ct * 8] = cvtpk(loA, hiA); \
        plane[wB + ct * 8] = cvtpk(loB, hiB); }

#define SCANROW(w) { \
        const float iE = __uint_as_float((w) << 16); \
        const float iO = __uint_as_float((w) & 0xffff0000u); \
        const float m0 = iE * KL0; \
        const float m1 = iO * KL1; \
        const float t_ = m0 + m1; \
        const float S_ = wave_incl_scan(t_); \
        const float ex = S_ - t_; \
        KL1 += ex + m0; \
        KL0 += ex; }

    const unsigned* __restrict__ prow = plane + lane;

    for (int band = 0; band < 8; ++band) {
        // ---- A frags: rows p = band*16 + l15 (clamped), hi-only ----
        int arow = band * 16 + l15; if (arow > 126) arow = 126;
        const float* ap = U + (size_t)arow * DD + k8;
        bf16x8 ak0 = dfrag_hi(ap,      ap + DD);
        bf16x8 ak1 = dfrag_hi(ap + 32, ap + DD + 32);

        FOR8(CTSTEP)   // inc[16][128] (packed bf16 pairs) -> plane

        // ---- Goursat scan, depth-2 LDS prefetch (wave-private, in-order) ----
        unsigned e = prow[0];
        unsigned f = prow[PSTR];
        #pragma unroll
        for (int r = 0; r < 13; ++r) {
            unsigned n = prow[(r + 2) * PSTR];
            SCANROW(e)
            e = f; f = n;
        }
        if (band < 7) {
            unsigned n = prow[15 * PSTR];
            SCANROW(e)                        // row 13
            e = f; f = n;
            SCANROW(e)                        // row 14
            SCANROW(f)                        // row 15
        } else {
            SCANROW(e)                        // row 13
            SCANROW(f)                        // row 14 (p=127 phantom)
        }
    }

    if (lane == 63) Kout[(size_t)g * 4096 + a * 64 + b] = KL1;   // K[127][127]
}

// Deterministic weighted reduction + the mean((X0-Y0)^2) term.
__global__ void sig_reduce_kernel(const float* __restrict__ X,
                                  const float* __restrict__ Y,
                                  const float* __restrict__ Kws,
                                  float* __restrict__ out)
{
    const int t = threadIdx.x;
    double accK = 0.0, acc2 = 0.0;
    for (int i = t; i < 4096; i += 256) {
        const int a = i >> 6, b = i & 63;
        if (a <= b) {
            const double w = (a == b) ? 1.0 : 2.0;
            accK += w * (double)Kws[i];           // XX
            accK += w * (double)Kws[4096 + i];    // YY
        }
        accK -= 2.0 * (double)Kws[8192 + i];      // XY
        const float df = X[(size_t)a * (MM * DD) + b] - Y[(size_t)a * (MM * DD) + b];
        acc2 += (double)df * (double)df;
    }
    __shared__ double red[256];
    red[t] = accK / 4096.0 + acc2 / 4096.0;
    __syncthreads();
    for (int s = 128; s > 0; s >>= 1) {
        if (t < s) red[t] += red[t + s];
        __syncthreads();
    }
    if (t == 0) out[0] = (float)red[0];
}

extern "C" void kernel_launch(void* const* d_in, const int* in_sizes, int n_in,
                              void* d_out, int out_size, void* d_ws, size_t ws_size,
                              hipStream_t stream) {
    const float* X = (const float*)d_in[0];
    const float* Y = (const float*)d_in[1];
    float* Kws = (float*)d_ws;          // 3 * 4096 floats
    float* out = (float*)d_out;

    sig_goursat_kernel<<<dim3(2064), dim3(256), 0, stream>>>(X, Y, Kws);
    sig_reduce_kernel<<<dim3(1), dim3(256), 0, stream>>>(X, Y, Kws, out);
}

// Round 14
// 140.950 us; speedup vs baseline: 1.1005x; 1.1005x over previous
//
#include <hip/hip_runtime.h>
#include <math.h>

#define DD 64      // feature dim
#define MM 128     // time points per path
#define PSTR 66    // packed plane row stride (u32): reads (lane+2r)%32, writes <=2-way
#define PWORDS (16 * PSTR)   // 1056 u32 = 4224 B per buffer

typedef float  f32x4v __attribute__((ext_vector_type(4)));
typedef __bf16 bf16x8 __attribute__((ext_vector_type(8)));

#define FOR8(F)  F(0) F(1) F(2) F(3) F(4) F(5) F(6) F(7)
#define FOR16(F) FOR8(F) F(8) F(9) F(10) F(11) F(12) F(13) F(14) F(15)

union FragU { unsigned int u[4]; bf16x8 v; };

// RNE f32x2 -> packed bf16x2 (lo -> bits[15:0], hi -> bits[31:16])
__device__ __forceinline__ unsigned cvtpk(float lo, float hi) {
    unsigned r;
    asm("v_cvt_pk_bf16_f32 %0, %1, %2" : "=v"(r) : "v"(lo), "v"(hi));
    return r;
}

// quad_perm [1,0,3,2]: swap adjacent lanes (lane ^ 1)
__device__ __forceinline__ float qswap(float x) {
    int t = __builtin_amdgcn_update_dpp(0, __float_as_int(x), 0xB1, 0xF, 0xF, true);
    return __int_as_float(t);
}

// bf16 frag of (row1 - row0), 8 consecutive floats (hi bits, RNE)
__device__ __forceinline__ bf16x8 dfrag_hi(const float* __restrict__ r0,
                                           const float* __restrict__ r1) {
    float4 a0 = *(const float4*)r0, a1 = *(const float4*)(r0 + 4);
    float4 b0 = *(const float4*)r1, b1 = *(const float4*)(r1 + 4);
    FragU f;
    f.u[0] = cvtpk(b0.x - a0.x, b0.y - a0.y);
    f.u[1] = cvtpk(b0.z - a0.z, b0.w - a0.w);
    f.u[2] = cvtpk(b1.x - a1.x, b1.y - a1.y);
    f.u[3] = cvtpk(b1.z - a1.z, b1.w - a1.w);
    return f.v;
}

// ---- wave64 inclusive add-scan via DPP (proven rounds 2-13) ----
template<int CTRL, int RM, bool BC>
__device__ __forceinline__ float dpp_add(float x) {
    int t = __builtin_amdgcn_update_dpp(0, __float_as_int(x), CTRL, RM, 0xf, BC);
    return x + __int_as_float(t);
}
__device__ __forceinline__ float wave_incl_scan(float x) {
    x = dpp_add<0x111, 0xf, true >(x);   // row_shr:1
    x = dpp_add<0x112, 0xf, true >(x);   // row_shr:2
    x = dpp_add<0x114, 0xf, true >(x);   // row_shr:4
    x = dpp_add<0x118, 0xf, true >(x);   // row_shr:8
    x = dpp_add<0x142, 0xa, false>(x);   // row_bcast:15 -> rows 1,3
    x = dpp_add<0x143, 0xc, false>(x);   // row_bcast:31 -> rows 2,3
    return x;
}

// ROUND 14: intra-wave phase decoupling. r11's clean counters show each wave
// ~80% stalled on WITHIN-band serialization: scan reads wait on just-issued
// MFMA writes (in-order LDS FIFO), then the DPP chain runs with an empty MFMA
// pipe, then the next band's loads/MFMAs run with an empty VALU pipe.
// Fix: static double-buffer (bufA/bufB distinct arrays); per segment:
//   (1) batch-read band k's 16 packed rows into 16 NAMED regs -- oldest LDS
//       ops, data written one full segment ago -> near-zero wait;
//   (2) issue band k+1's A-loads + 16 MFMA + 16 packed ds_writes;
//   (3) scan math on registers, physically interleaved with (2) so the
//       scheduler fills DPP stalls with MFMA/ds/global issue.
// Packed-bf16 plane (r13, absmax 0.0): 2 x 4.2 KB LDS; 1-wave blocks;
// (64,3): ~170-reg cap, live ~125 -> no spill. Band loop rolled (I$).
__global__ __launch_bounds__(64, 3) void sig_goursat_kernel(
        const float* __restrict__ X, const float* __restrict__ Y,
        float* __restrict__ Kout)
{
    const int bid = blockIdx.x;
    int g, a, b;
    if (bid < 4160) {                  // symmetric grams, triangular index
        g = bid < 2080 ? 0 : 1;
        const int t = bid - g * 2080;
        float sq = sqrtf(4160.25f - 2.0f * (float)t);
        a = (int)(64.5f - sq);
        if (a < 0) a = 0; if (a > 63) a = 63;
        while (a > 0  && (a * (129 - a)) / 2 > t) --a;
        while (a < 63 && ((a + 1) * (128 - a)) / 2 <= t) ++a;
        b = a + (t - (a * (129 - a)) / 2);
    } else {
        const int t = bid - 4160;
        g = 2; a = t >> 6; b = t & 63;
    }

    const float* __restrict__ U = (g == 1 ? Y : X) + (size_t)a * (MM * DD);
    const float* __restrict__ V = (g == 0 ? X : Y) + (size_t)b * (MM * DD);

    const int lane = threadIdx.x;
    const int l15  = lane & 15;
    const int k8   = (lane >> 4) * 8;         // k-offset of this lane's frag
    const int rowg = (lane >> 4) * 4;         // C/D row group base
    const int par  = l15 & 1;

    __shared__ unsigned bufA[PWORDS];         // static dual band buffers
    __shared__ unsigned bufB[PWORDS];

    // ---- B-frag register table: 16 named bf16x8 (64 regs), built once ----
#define TBDECL(ct) bf16x8 tb0_##ct, tb1_##ct;
    FOR8(TBDECL)
#define TBUILD(ct) { int brow_ = ct * 16 + l15; if (brow_ > 126) brow_ = 126; \
        const float* vp_ = V + (size_t)brow_ * DD + k8; \
        tb0_##ct = dfrag_hi(vp_,      vp_ + DD); \
        tb1_##ct = dfrag_hi(vp_ + 32, vp_ + DD + 32); }
    FOR8(TBUILD)

    float KL0 = 1.0f, KL1 = 1.0f;             // K[0][2l], K[0][2l+1] = 1

    // packed writer (r13-proven): even l15 lanes own rows rowg+0/1,
    // odd own rowg+2/3; word = row*PSTR + ct*8 + (l15>>1)
    const int wA = (rowg + 2 * par) * PSTR + (l15 >> 1);

#define CTSTEP(ct, bp) { \
        f32x4v c = {0.f, 0.f, 0.f, 0.f}; \
        c = __builtin_amdgcn_mfma_f32_16x16x32_bf16(ak0, tb0_##ct, c, 0, 0, 0); \
        c = __builtin_amdgcn_mfma_f32_16x16x32_bf16(ak1, tb1_##ct, c, 0, 0, 0); \
        const float n0 = qswap(c[0]); const float n1 = qswap(c[1]); \
        const float n2 = qswap(c[2]); const float n3 = qswap(c[3]); \
        const float loA = par ? n2 : c[0]; const float hiA = par ? c[2] : n0; \
        const float loB = par ? n3 : c[1]; const float hiB = par ? c[3] : n1; \
        (bp)[wA + (ct) * 8]        = cvtpk(loA, hiA); \
        (bp)[wA + PSTR + (ct) * 8] = cvtpk(loB, hiB); }

#define ALOAD(sidx) \
        int arow = (sidx) * 16 + l15; if (arow > 126) arow = 126; \
        const float* ap = U + (size_t)arow * DD + k8; \
        bf16x8 ak0 = dfrag_hi(ap,      ap + DD); \
        bf16x8 ak1 = dfrag_hi(ap + 32, ap + DD + 32);

#define SCANROW(w) { \
        const float iE = __uint_as_float((w) << 16); \
        const float iO = __uint_as_float((w) & 0xffff0000u); \
        const float m0 = iE * KL0; \
        const float m1 = iO * KL1; \
        const float t_ = m0 + m1; \
        const float S_ = wave_incl_scan(t_); \
        const float ex = S_ - t_; \
        KL1 += ex + m0; \
        KL0 += ex; }

#define WDECL(i) unsigned w##i = rp[(i) * PSTR];

    // segment: batch-read scan rows (oldest), stage next band, scan math
#define SEGMENT(sbuf, sidx, dbuf) { \
        const unsigned* __restrict__ rp = (sbuf) + lane; \
        FOR16(WDECL) \
        ALOAD(sidx) \
        CTSTEP(0, dbuf) CTSTEP(1, dbuf) \
        SCANROW(w0)  CTSTEP(2, dbuf) \
        SCANROW(w1)  CTSTEP(3, dbuf) \
        SCANROW(w2)  CTSTEP(4, dbuf) \
        SCANROW(w3)  CTSTEP(5, dbuf) \
        SCANROW(w4)  CTSTEP(6, dbuf) \
        SCANROW(w5)  CTSTEP(7, dbuf) \
        SCANROW(w6)  SCANROW(w7)  SCANROW(w8)  SCANROW(w9) \
        SCANROW(w10) SCANROW(w11) SCANROW(w12) SCANROW(w13) \
        SCANROW(w14) SCANROW(w15) }

#define STAGE(sidx, dbuf) { \
        ALOAD(sidx) \
        CTSTEP(0, dbuf) CTSTEP(1, dbuf) CTSTEP(2, dbuf) CTSTEP(3, dbuf) \
        CTSTEP(4, dbuf) CTSTEP(5, dbuf) CTSTEP(6, dbuf) CTSTEP(7, dbuf) }

    STAGE(0, bufA)                            // prologue: band 0 -> A

    #pragma unroll 1
    for (int k = 0; k < 3; ++k) {             // bands 0..5 scanned
        SEGMENT(bufA, 2 * k + 1, bufB)        // scan band 2k,   stage 2k+1
        SEGMENT(bufB, 2 * k + 2, bufA)        // scan band 2k+1, stage 2k+2
    }
    SEGMENT(bufA, 7, bufB)                    // scan band 6, stage band 7

    {   // tail: scan band 7 (15 real rows; p=127 phantom)
        const unsigned* __restrict__ rp = bufB + lane;
        FOR16(WDECL)
        SCANROW(w0)  SCANROW(w1)  SCANROW(w2)  SCANROW(w3)
        SCANROW(w4)  SCANROW(w5)  SCANROW(w6)  SCANROW(w7)
        SCANROW(w8)  SCANROW(w9)  SCANROW(w10) SCANROW(w11)
        SCANROW(w12) SCANROW(w13) SCANROW(w14)
        (void)w15;
    }

    if (lane == 63) Kout[(size_t)g * 4096 + a * 64 + b] = KL1;   // K[127][127]
}

// Deterministic weighted reduction + the mean((X0-Y0)^2) term.
__global__ void sig_reduce_kernel(const float* __restrict__ X,
                                  const float* __restrict__ Y,
                                  const float* __restrict__ Kws,
                                  float* __restrict__ out)
{
    const int t = threadIdx.x;
    double accK = 0.0, acc2 = 0.0;
    for (int i = t; i < 4096; i += 256) {
        const int a = i >> 6, b = i & 63;
        if (a <= b) {
            const double w = (a == b) ? 1.0 : 2.0;
            accK += w * (double)Kws[i];           // XX
            accK += w * (double)Kws[4096 + i];    // YY
        }
        accK -= 2.0 * (double)Kws[8192 + i];      // XY
        const float df = X[(size_t)a * (MM * DD) + b] - Y[(size_t)a * (MM * DD) + b];
        acc2 += (double)df * (double)df;
    }
    __shared__ double red[256];
    red[t] = accK / 4096.0 + acc2 / 4096.0;
    __syncthreads();
    for (int s = 128; s > 0; s >>= 1) {
        if (t < s) red[t] += red[t + s];
        __syncthreads();
    }
    if (t == 0) out[0] = (float)red[0];
}

extern "C" void kernel_launch(void* const* d_in, const int* in_sizes, int n_in,
                              void* d_out, int out_size, void* d_ws, size_t ws_size,
                              hipStream_t stream) {
    const float* X = (const float*)d_in[0];
    const float* Y = (const float*)d_in[1];
    float* Kws = (float*)d_ws;          // 3 * 4096 floats
    float* out = (float*)d_out;

    sig_goursat_kernel<<<dim3(8256), dim3(64), 0, stream>>>(X, Y, Kws);
    sig_reduce_kernel<<<dim3(1), dim3(256), 0, stream>>>(X, Y, Kws, out);
}